// Round 12
// baseline (36.075 us; speedup 1.0000x reference)
//
#include <hip/hip_runtime.h>

#define EPS 1e-8f

// Shapes fixed per reference: x [B=8, N=8192, D=512] fp32, scalar fp32 out.
#define B_DIM 8
#define N_DIM 8192
#define D_DIM 512
#define CHUNKS 256   // K1 grid = B*CHUNKS = 2048 blocks (8/CU, 32 waves/CU)
#define FIX_SCALE 1099511627776.0   // 2^40 fixed-point scale for deterministic sum

typedef float fx4 __attribute__((ext_vector_type(4)));

// ws control slots (after the 4 MB partial buffer):
// ctl[0]=acc  ctl[1]=ticket  ctl[2]=acc2  ctl[3]=ticket2  ctl[4]=out2(bits)

// K1: 256 threads (4 waves). Each wave: 8 rows, 4 rows/iteration, register
// double-buffer. Lane l owns d-slice [8l,8l+8). Block 0 zeroes all ctl slots.
__global__ __launch_bounds__(256) void k1_partial(const float* __restrict__ x,
                                                  float* __restrict__ partial,
                                                  unsigned long long* __restrict__ ctl) {
    if (blockIdx.x == 0 && threadIdx.x < 5) ctl[threadIdx.x] = 0ULL;

    constexpr int rowsPerChunk = N_DIM / CHUNKS;   // 32
    constexpr int rowsPerWave  = rowsPerChunk / 4; // 8
    constexpr int ITERS        = rowsPerWave / 4;  // 2

    const int blk   = blockIdx.x;
    const int b     = blk >> 8;            // / CHUNKS
    const int chunk = blk & (CHUNKS - 1);
    const int wave  = threadIdx.x >> 6;    // 0..3
    const int lane  = threadIdx.x & 63;

    const long long rowStart = (long long)b * N_DIM
                             + (long long)chunk * rowsPerChunk
                             + (long long)wave * rowsPerWave;

    float accv[8];
    #pragma unroll
    for (int k = 0; k < 8; ++k) accv[k] = 0.0f;

    const float* base = x + rowStart * D_DIM + lane * 8;

    fx4 v[2][4][2];

    #pragma unroll
    for (int i = 0; i < 4; ++i) {
        v[0][i][0] = *(const fx4*)(base + i * D_DIM);
        v[0][i][1] = *(const fx4*)(base + i * D_DIM + 4);
    }
    base += 4 * D_DIM;

    #pragma unroll
    for (int it = 0; it < ITERS; ++it) {
        const int cur = it & 1;
        const int nxt = cur ^ 1;

        if (it < ITERS - 1) {
            #pragma unroll
            for (int i = 0; i < 4; ++i) {
                v[nxt][i][0] = *(const fx4*)(base + i * D_DIM);
                v[nxt][i][1] = *(const fx4*)(base + i * D_DIM + 4);
            }
            base += 4 * D_DIM;
        }

        float ss[4];
        #pragma unroll
        for (int i = 0; i < 4; ++i) {
            ss[i] = v[cur][i][0].x*v[cur][i][0].x + v[cur][i][0].y*v[cur][i][0].y
                  + v[cur][i][0].z*v[cur][i][0].z + v[cur][i][0].w*v[cur][i][0].w
                  + v[cur][i][1].x*v[cur][i][1].x + v[cur][i][1].y*v[cur][i][1].y
                  + v[cur][i][1].z*v[cur][i][1].z + v[cur][i][1].w*v[cur][i][1].w;
        }

        #pragma unroll
        for (int off = 1; off < 64; off <<= 1) {
            #pragma unroll
            for (int i = 0; i < 4; ++i) ss[i] += __shfl_xor(ss[i], off);
        }

        #pragma unroll
        for (int i = 0; i < 4; ++i) {
            const float inv = 1.0f / fmaxf(sqrtf(ss[i]), EPS);
            accv[0] += v[cur][i][0].x * inv;
            accv[1] += v[cur][i][0].y * inv;
            accv[2] += v[cur][i][0].z * inv;
            accv[3] += v[cur][i][0].w * inv;
            accv[4] += v[cur][i][1].x * inv;
            accv[5] += v[cur][i][1].y * inv;
            accv[6] += v[cur][i][1].z * inv;
            accv[7] += v[cur][i][1].w * inv;
        }
    }

    __shared__ float lds[4][D_DIM];
    float* dst = &lds[wave][lane * 8];
    #pragma unroll
    for (int k = 0; k < 8; ++k) dst[k] = accv[k];
    __syncthreads();

    for (int d = threadIdx.x; d < D_DIM; d += 256) {
        float s = lds[0][d] + lds[1][d] + lds[2][d] + lds[3][d];
        partial[(long long)blk * D_DIM + d] = s;
    }
}

// K2: 64 blocks = (b, g) with g = d-group of 64 d's; 512 threads.
// Thread (q=tid>>4, quad=tid&15) reads chunks c=8q..8q+7 at d-quad
// g*64+quad*4 as contiguous fx4 (16-thread group covers 256B per chunk row),
// 4-deep ILP. LDS tree-reduce over q, square, 16-lane reduce -> block ssq.
// Fixed-point u64 atomic (order-independent = deterministic); ticket-63
// block writes the final scalar.
__global__ __launch_bounds__(512) void k2_batch(const float* __restrict__ partial,
                                                unsigned long long* __restrict__ acc,
                                                unsigned long long* __restrict__ ticket,
                                                float* __restrict__ out) {
    const int b    = blockIdx.x >> 3;
    const int g    = blockIdx.x & 7;
    const int quad = threadIdx.x & 15;   // d-quad within group
    const int q    = threadIdx.x >> 4;   // 0..31 chunk-set

    const float* p = partial + (long long)b * CHUNKS * D_DIM
                   + (long long)g * 64 + quad * 4;

    fx4 s0 = {0,0,0,0}, s1 = {0,0,0,0}, s2 = {0,0,0,0}, s3 = {0,0,0,0};
    const long long cbase = (long long)q * 8;
    s0 += *(const fx4*)(p + (cbase + 0) * D_DIM);
    s1 += *(const fx4*)(p + (cbase + 1) * D_DIM);
    s2 += *(const fx4*)(p + (cbase + 2) * D_DIM);
    s3 += *(const fx4*)(p + (cbase + 3) * D_DIM);
    s0 += *(const fx4*)(p + (cbase + 4) * D_DIM);
    s1 += *(const fx4*)(p + (cbase + 5) * D_DIM);
    s2 += *(const fx4*)(p + (cbase + 6) * D_DIM);
    s3 += *(const fx4*)(p + (cbase + 7) * D_DIM);
    const fx4 s = (s0 + s1) + (s2 + s3);

    __shared__ fx4 lds[32][16];
    lds[q][quad] = s;
    __syncthreads();

    // stage 2: 128 threads fold 32 q-rows -> 8
    if (threadIdx.x < 128) {
        const int q2 = threadIdx.x >> 4;   // 0..7
        const int qd = threadIdx.x & 15;
        lds[q2][qd] = (lds[q2][qd] + lds[q2 + 8][qd])
                    + (lds[q2 + 16][qd] + lds[q2 + 24][qd]);
    }
    __syncthreads();

    // stage 3: 16 threads (lanes 0..15 of wave 0) finish
    if (threadIdx.x < 16) {
        fx4 t = {0,0,0,0};
        #pragma unroll
        for (int q2 = 0; q2 < 8; ++q2) t += lds[q2][threadIdx.x];
        float v = t.x*t.x + t.y*t.y + t.z*t.z + t.w*t.w;
        #pragma unroll
        for (int off = 1; off < 16; off <<= 1) v += __shfl_xor(v, off);

        if (threadIdx.x == 0) {
            const long long q64 = (long long)((double)v * FIX_SCALE);
            atomicAdd(acc, (unsigned long long)q64);
            __threadfence();
            const unsigned long long t63 = atomicAdd(ticket, 1ULL);
            if (t63 == (B_DIM * 8 - 1)) {
                const unsigned long long totu = atomicAdd(acc, 0ULL);
                const double tot_d = (double)(long long)totu / FIX_SCALE;
                out[0] = (float)(tot_d / ((double)N_DIM * (double)N_DIM * (double)B_DIM));
            }
        }
    }
}

extern "C" void kernel_launch(void* const* d_in, const int* in_sizes, int n_in,
                              void* d_out, int out_size, void* d_ws, size_t ws_size,
                              hipStream_t stream) {
    const float* x = (const float*)d_in[0];
    float* out = (float*)d_out;

    float* partial = (float*)d_ws;                                  // 8*256*512 floats = 4 MB
    unsigned long long* ctl = (unsigned long long*)((char*)d_ws +
                              (size_t)B_DIM * CHUNKS * D_DIM * sizeof(float));

    k1_partial<<<dim3(B_DIM * CHUNKS), dim3(256), 0, stream>>>(x, partial, ctl);
    k2_batch<<<dim3(B_DIM * 8), dim3(512), 0, stream>>>(partial, ctl + 0, ctl + 1, out);

    // timing probe: identical K2 on the same partials, scratch outputs.
    // dur = K1 + 2*K2  ->  resolves K1 vs K2 decomposition.
    k2_batch<<<dim3(B_DIM * 8), dim3(512), 0, stream>>>(partial, ctl + 2, ctl + 3,
                                                        (float*)(ctl + 4));
}

// Round 13
// 33.388 us; speedup vs baseline: 1.0805x; 1.0805x over previous
//
#include <hip/hip_runtime.h>

#define EPS 1e-8f

// Shapes fixed per reference: x [B=8, N=8192, D=512] fp32, scalar fp32 out.
#define B_DIM 8
#define N_DIM 8192
#define D_DIM 512
#define CHUNKS 256   // K1 grid = B*CHUNKS = 2048 blocks (8/CU, 32 waves/CU)
#define FIX_SCALE 1099511627776.0   // 2^40 fixed-point scale for deterministic sum

typedef float fx4 __attribute__((ext_vector_type(4)));

// K1: 256 threads (4 waves). Each wave: 8 rows, 4 rows/iteration, register
// double-buffer. Lane l owns d-slice [8l,8l+8). Block 0 zeroes ctl slots
// (used only by K2b, two kernels later -> stream order is sufficient).
__global__ __launch_bounds__(256) void k1_partial(const float* __restrict__ x,
                                                  float* __restrict__ partial,
                                                  unsigned long long* __restrict__ ctl) {
    if (blockIdx.x == 0 && threadIdx.x < 2) ctl[threadIdx.x] = 0ULL;

    constexpr int rowsPerChunk = N_DIM / CHUNKS;   // 32
    constexpr int rowsPerWave  = rowsPerChunk / 4; // 8
    constexpr int ITERS        = rowsPerWave / 4;  // 2

    const int blk   = blockIdx.x;
    const int b     = blk >> 8;            // / CHUNKS
    const int chunk = blk & (CHUNKS - 1);
    const int wave  = threadIdx.x >> 6;    // 0..3
    const int lane  = threadIdx.x & 63;

    const long long rowStart = (long long)b * N_DIM
                             + (long long)chunk * rowsPerChunk
                             + (long long)wave * rowsPerWave;

    float accv[8];
    #pragma unroll
    for (int k = 0; k < 8; ++k) accv[k] = 0.0f;

    const float* base = x + rowStart * D_DIM + lane * 8;

    fx4 v[2][4][2];

    #pragma unroll
    for (int i = 0; i < 4; ++i) {
        v[0][i][0] = *(const fx4*)(base + i * D_DIM);
        v[0][i][1] = *(const fx4*)(base + i * D_DIM + 4);
    }
    base += 4 * D_DIM;

    #pragma unroll
    for (int it = 0; it < ITERS; ++it) {
        const int cur = it & 1;
        const int nxt = cur ^ 1;

        if (it < ITERS - 1) {
            #pragma unroll
            for (int i = 0; i < 4; ++i) {
                v[nxt][i][0] = *(const fx4*)(base + i * D_DIM);
                v[nxt][i][1] = *(const fx4*)(base + i * D_DIM + 4);
            }
            base += 4 * D_DIM;
        }

        float ss[4];
        #pragma unroll
        for (int i = 0; i < 4; ++i) {
            ss[i] = v[cur][i][0].x*v[cur][i][0].x + v[cur][i][0].y*v[cur][i][0].y
                  + v[cur][i][0].z*v[cur][i][0].z + v[cur][i][0].w*v[cur][i][0].w
                  + v[cur][i][1].x*v[cur][i][1].x + v[cur][i][1].y*v[cur][i][1].y
                  + v[cur][i][1].z*v[cur][i][1].z + v[cur][i][1].w*v[cur][i][1].w;
        }

        #pragma unroll
        for (int off = 1; off < 64; off <<= 1) {
            #pragma unroll
            for (int i = 0; i < 4; ++i) ss[i] += __shfl_xor(ss[i], off);
        }

        #pragma unroll
        for (int i = 0; i < 4; ++i) {
            const float inv = 1.0f / fmaxf(sqrtf(ss[i]), EPS);
            accv[0] += v[cur][i][0].x * inv;
            accv[1] += v[cur][i][0].y * inv;
            accv[2] += v[cur][i][0].z * inv;
            accv[3] += v[cur][i][0].w * inv;
            accv[4] += v[cur][i][1].x * inv;
            accv[5] += v[cur][i][1].y * inv;
            accv[6] += v[cur][i][1].z * inv;
            accv[7] += v[cur][i][1].w * inv;
        }
    }

    __shared__ float lds[4][D_DIM];
    float* dst = &lds[wave][lane * 8];
    #pragma unroll
    for (int k = 0; k < 8; ++k) dst[k] = accv[k];
    __syncthreads();

    for (int d = threadIdx.x; d < D_DIM; d += 256) {
        float s = lds[0][d] + lds[1][d] + lds[2][d] + lds[3][d];
        partial[(long long)blk * D_DIM + d] = s;
    }
}

// K2a: fold chunks 256 -> 8. Grid = 256 blocks = (b, t, dg): b<8 batches,
// t<8 chunk-supergroups (32 chunks each), dg<4 d-slices (128 d's each).
// 512 threads: q = tid>>5 (0..15), dq = tid&31 (d-quad). Thread sums chunks
// 32t+q and 32t+16+q at its fx4; LDS tree 16->1; 32 threads write 512 B.
__global__ __launch_bounds__(512) void k2a_fold(const float* __restrict__ partial,
                                                float* __restrict__ partial2) {
    const int blk = blockIdx.x;
    const int b   = blk >> 5;          // /32
    const int t   = (blk >> 2) & 7;
    const int dg  = blk & 3;
    const int q   = threadIdx.x >> 5;  // 0..15
    const int dq  = threadIdx.x & 31;  // 0..31
    const int d   = dg * 128 + dq * 4;

    const float* p = partial + (long long)b * CHUNKS * D_DIM + d;
    const long long c0 = (long long)(t * 32 + q);
    const long long c1 = c0 + 16;

    fx4 s = *(const fx4*)(p + c0 * D_DIM);
    s    += *(const fx4*)(p + c1 * D_DIM);

    __shared__ fx4 lds[16][32];
    lds[q][dq] = s;
    __syncthreads();

    if (q < 8) lds[q][dq] += lds[q + 8][dq];
    __syncthreads();
    if (q < 4) lds[q][dq] += lds[q + 4][dq];
    __syncthreads();
    if (q < 2) lds[q][dq] += lds[q + 2][dq];
    __syncthreads();
    if (q == 0) {
        const fx4 r = lds[0][dq] + lds[1][dq];
        *(fx4*)(partial2 + ((long long)(b * 8 + t) * D_DIM) + d) = r;
    }
}

// K2b: 64 blocks = (b, g), 512 threads: q = tid>>6 (0..7) = supergroup,
// dl = tid&63. One load/thread from partial2 (128 KB total), LDS fold 8,
// square, 64-lane butterfly -> block ssq. Fixed-point u64 atomic add
// (order-independent = deterministic); ticket-63 block writes the scalar.
__global__ __launch_bounds__(512) void k2b_finish(const float* __restrict__ partial2,
                                                  unsigned long long* __restrict__ acc,
                                                  unsigned long long* __restrict__ ticket,
                                                  float* __restrict__ out) {
    const int b  = blockIdx.x >> 3;
    const int g  = blockIdx.x & 7;
    const int dl = threadIdx.x & 63;
    const int q  = threadIdx.x >> 6;   // 0..7
    const int d  = g * 64 + dl;

    const float s = partial2[((long long)(b * 8 + q) * D_DIM) + d];

    __shared__ float lds[8][64];
    lds[q][dl] = s;
    __syncthreads();

    if (q == 0) {
        float tot = 0.0f;
        #pragma unroll
        for (int w = 0; w < 8; ++w) tot += lds[w][dl];
        float v = tot * tot;
        #pragma unroll
        for (int off = 1; off < 64; off <<= 1) v += __shfl_xor(v, off);

        if (dl == 0) {
            const long long q64 = (long long)((double)v * FIX_SCALE);
            atomicAdd(acc, (unsigned long long)q64);
            __threadfence();
            const unsigned long long t63 = atomicAdd(ticket, 1ULL);
            if (t63 == (B_DIM * 8 - 1)) {
                const unsigned long long totu = atomicAdd(acc, 0ULL);
                const double tot_d = (double)(long long)totu / FIX_SCALE;
                out[0] = (float)(tot_d / ((double)N_DIM * (double)N_DIM * (double)B_DIM));
            }
        }
    }
}

extern "C" void kernel_launch(void* const* d_in, const int* in_sizes, int n_in,
                              void* d_out, int out_size, void* d_ws, size_t ws_size,
                              hipStream_t stream) {
    const float* x = (const float*)d_in[0];
    float* out = (float*)d_out;

    float* partial = (float*)d_ws;                                  // 8*256*512 floats = 4 MB
    float* partial2 = partial + (size_t)B_DIM * CHUNKS * D_DIM;     // 8*8*512 floats = 128 KB
    unsigned long long* ctl = (unsigned long long*)(partial2 + (size_t)B_DIM * 8 * D_DIM);

    k1_partial<<<dim3(B_DIM * CHUNKS), dim3(256), 0, stream>>>(x, partial, ctl);
    k2a_fold<<<dim3(256), dim3(512), 0, stream>>>(partial, partial2);
    k2b_finish<<<dim3(B_DIM * 8), dim3(512), 0, stream>>>(partial2, ctl + 0, ctl + 1, out);
}